// Round 1
// baseline (906.753 us; speedup 1.0000x reference)
//
#include <hip/hip_runtime.h>
#include <hip/hip_bf16.h>
#include <stdint.h>

#define B_    2
#define S_    2048
#define H_    32
#define KVH_  8
#define D_    128

typedef __bf16 bf16x8 __attribute__((ext_vector_type(8)));
typedef unsigned short u16x8 __attribute__((ext_vector_type(8)));
typedef float f32x4 __attribute__((ext_vector_type(4)));

// softmax scale folded with log2(e) so we can use exp2
__device__ constexpr float SCALE_LOG2E = 0.08838834764831845f * 1.4426950408889634f;

__device__ __forceinline__ unsigned short f2bf(float f) {
    unsigned int u = __builtin_bit_cast(unsigned int, f);
    u = (u + 0x7FFFu + ((u >> 16) & 1u)) >> 16;   // round-to-nearest-even
    return (unsigned short)u;
}

// ---------------------------------------------------------------------------
// Prepass 1: k [B,S,KVH,D] fp32 -> kbuf [B,KVH,S,D] bf16
// ---------------------------------------------------------------------------
__global__ __launch_bounds__(256) void convert_k(const float* __restrict__ k,
                                                 unsigned short* __restrict__ kbuf) {
    int idx = blockIdx.x * 256 + threadIdx.x;        // one thread per 4 elements
    int d4  = (idx & 31) * 4;                        // 0..124
    int s   = (idx >> 5) & (S_ - 1);
    int kvh = (idx >> 16) & (KVH_ - 1);
    int b   = idx >> 19;
    const float4* src = (const float4*)(k + (((size_t)b * S_ + s) * KVH_ + kvh) * D_ + d4);
    float4 x = *src;
    ushort4 o;
    o.x = f2bf(x.x); o.y = f2bf(x.y); o.z = f2bf(x.z); o.w = f2bf(x.w);
    *(ushort4*)(kbuf + (((size_t)b * KVH_ + kvh) * S_ + s) * D_ + d4) = o;
}

// ---------------------------------------------------------------------------
// Prepass 2: v [B,S,KVH,D] fp32 -> vbuf [B,KVH,D,S] bf16 (transpose via LDS)
// ---------------------------------------------------------------------------
__global__ __launch_bounds__(256) void transpose_v(const float* __restrict__ v,
                                                   unsigned short* __restrict__ vbuf) {
    __shared__ float tile[32][33];
    int bid = blockIdx.x;
    int dt  = bid & 3;                // D/32
    int st  = (bid >> 2) & 63;        // S/32
    int kvh = (bid >> 8) & 7;
    int b   = bid >> 11;
    int t   = threadIdx.x;

    int row  = t >> 3;                // s within tile, 0..31
    int col4 = (t & 7) * 4;           // d within tile
    const float* src = v + (((size_t)b * S_ + st * 32 + row) * KVH_ + kvh) * D_ + dt * 32 + col4;
    float4 x = *(const float4*)src;
    tile[row][col4 + 0] = x.x; tile[row][col4 + 1] = x.y;
    tile[row][col4 + 2] = x.z; tile[row][col4 + 3] = x.w;
    __syncthreads();

    int drow = t >> 3;                // d within tile
    int s4   = (t & 7) * 4;           // s within tile
    ushort4 o;
    o.x = f2bf(tile[s4 + 0][drow]);
    o.y = f2bf(tile[s4 + 1][drow]);
    o.z = f2bf(tile[s4 + 2][drow]);
    o.w = f2bf(tile[s4 + 3][drow]);
    unsigned short* dst = vbuf + (((size_t)b * KVH_ + kvh) * D_ + dt * 32 + drow) * S_ + st * 32 + s4;
    *(ushort4*)dst = o;
}

// ---------------------------------------------------------------------------
// Main flash-attention kernel.
// Block = 256 threads = 4 waves; each wave owns 16 q-rows independently
// (no block-wide barrier in K-loop; causal trip count differs per wave).
// QK^T:  S[16q x 32k] via mfma_16x16x32 (A=Q frags, B=K rows, contiguous)
// PV  :  O^T[128d x 16q] via mfma (A=V^T from vbuf contiguous, B=P^T via LDS)
// ---------------------------------------------------------------------------
__global__ __launch_bounds__(256, 2)
void attn_fwd(const float* __restrict__ q,
              const unsigned short* __restrict__ kbuf,
              const unsigned short* __restrict__ vbuf,
              float* __restrict__ out)
{
    const int gid   = blockIdx.x;
    const int qtile = gid & 31;          // S/64
    const int h     = (gid >> 5) & 31;
    const int b     = gid >> 10;
    const int kvh   = h >> 2;            // rep = 4 (repeat_interleave: h -> h/4)

    const int tid  = threadIdx.x;
    const int wave = tid >> 6;
    const int lane = tid & 63;
    const int c    = lane & 15;          // MFMA col index (key for S, qrow for O^T)
    const int g    = lane >> 4;          // lane group

    const int q0 = qtile * 64 + wave * 16;   // first q-row of this wave

    __shared__ __align__(16) unsigned short p_lds[4][16][40];  // stride 40: 16B-aligned b128 reads, low conflicts
    __shared__ float sm_stat[4][16];

    // ---- Q fragments: A[row=c][k = 32*ch + 8*g + j], fp32 -> bf16 ----
    bf16x8 qf[4];
    {
        const float* qp = q + ((size_t)b * S_ + (q0 + c)) * (H_ * D_) + h * D_ + g * 8;
        #pragma unroll
        for (int ch = 0; ch < 4; ++ch) {
            float4 a  = *(const float4*)(qp + ch * 32);
            float4 bb = *(const float4*)(qp + ch * 32 + 4);
            u16x8 t;
            t[0] = f2bf(a.x);  t[1] = f2bf(a.y);  t[2] = f2bf(a.z);  t[3] = f2bf(a.w);
            t[4] = f2bf(bb.x); t[5] = f2bf(bb.y); t[6] = f2bf(bb.z); t[7] = f2bf(bb.w);
            qf[ch] = __builtin_bit_cast(bf16x8, t);
        }
    }

    const unsigned short* kbase = kbuf + ((size_t)b * KVH_ + kvh) * S_ * D_;
    const unsigned short* vbase = vbuf + ((size_t)b * KVH_ + kvh) * (size_t)D_ * S_;

    f32x4 acc[8];                         // O^T accum: [d-tile mt][reg r], d = 16*mt + 4*g + r, qcol = c
    #pragma unroll
    for (int i = 0; i < 8; ++i) acc[i] = (f32x4){0.f, 0.f, 0.f, 0.f};
    float m_run[4], l_run[4];
    #pragma unroll
    for (int r = 0; r < 4; ++r) { m_run[r] = -INFINITY; l_run[r] = 0.f; }

    const int kv_end = q0 + 16;
    for (int k0 = 0; k0 < kv_end; k0 += 32) {
        // ---- K fragments: B[k = 32*ch + 8*g + j][col = key = k0 + 16t + c] ----
        bf16x8 kf[2][4];
        #pragma unroll
        for (int t = 0; t < 2; ++t)
            #pragma unroll
            for (int ch = 0; ch < 4; ++ch)
                kf[t][ch] = *(const bf16x8*)(kbase + (size_t)(k0 + t * 16 + c) * D_ + ch * 32 + g * 8);

        // ---- S = Q K^T : lane holds S[q0 + 4g + r][k0 + 16t + c] ----
        f32x4 sv[2];
        sv[0] = (f32x4){0.f, 0.f, 0.f, 0.f};
        sv[1] = (f32x4){0.f, 0.f, 0.f, 0.f};
        #pragma unroll
        for (int ch = 0; ch < 4; ++ch) {
            sv[0] = __builtin_amdgcn_mfma_f32_16x16x32_bf16(qf[ch], kf[0][ch], sv[0], 0, 0, 0);
            sv[1] = __builtin_amdgcn_mfma_f32_16x16x32_bf16(qf[ch], kf[1][ch], sv[1], 0, 0, 0);
        }

        // ---- causal mask (only diagonal tiles need it) ----
        if (k0 + 31 > q0) {
            #pragma unroll
            for (int t = 0; t < 2; ++t)
                #pragma unroll
                for (int r = 0; r < 4; ++r) {
                    if (k0 + t * 16 + c > q0 + 4 * g + r) sv[t][r] = -INFINITY;
                }
        }

        // ---- online softmax: row stats via 16-lane xor reduce ----
        float mx[4];
        #pragma unroll
        for (int r = 0; r < 4; ++r) mx[r] = fmaxf(sv[0][r], sv[1][r]);
        #pragma unroll
        for (int off = 1; off < 16; off <<= 1) {
            #pragma unroll
            for (int r = 0; r < 4; ++r)
                mx[r] = fmaxf(mx[r], __shfl_xor(mx[r], off));
        }

        float alpha[4], p0[4], p1[4], sum[4];
        #pragma unroll
        for (int r = 0; r < 4; ++r) {
            float mn = fmaxf(m_run[r], mx[r]);
            alpha[r] = exp2f((m_run[r] - mn) * SCALE_LOG2E);
            m_run[r] = mn;
            p0[r] = exp2f((sv[0][r] - mn) * SCALE_LOG2E);
            p1[r] = exp2f((sv[1][r] - mn) * SCALE_LOG2E);
            sum[r] = p0[r] + p1[r];
        }
        #pragma unroll
        for (int off = 1; off < 16; off <<= 1) {
            #pragma unroll
            for (int r = 0; r < 4; ++r)
                sum[r] += __shfl_xor(sum[r], off);
        }
        #pragma unroll
        for (int r = 0; r < 4; ++r)
            l_run[r] = l_run[r] * alpha[r] + sum[r];

        // ---- broadcast alpha (row domain -> col domain) via wave-local LDS ----
        if (c == 0) {
            #pragma unroll
            for (int r = 0; r < 4; ++r) sm_stat[wave][4 * g + r] = alpha[r];
        }
        asm volatile("s_waitcnt lgkmcnt(0)" ::: "memory");
        float acol = sm_stat[wave][c];

        // ---- write P (bf16) to wave-local LDS: p_lds[qrow][key] ----
        #pragma unroll
        for (int r = 0; r < 4; ++r) {
            p_lds[wave][4 * g + r][c]      = f2bf(p0[r]);
            p_lds[wave][4 * g + r][16 + c] = f2bf(p1[r]);
        }

        // ---- rescale O^T accumulators by alpha of their q-column ----
        #pragma unroll
        for (int mt = 0; mt < 8; ++mt) {
            acc[mt][0] *= acol; acc[mt][1] *= acol;
            acc[mt][2] *= acol; acc[mt][3] *= acol;
        }

        asm volatile("s_waitcnt lgkmcnt(0)" ::: "memory");
        // B-frag for PV: B[k = 8g + j][col = qrow = c] = P[c][8g + j]
        bf16x8 pf = *(const bf16x8*)&p_lds[wave][c][g * 8];

        // ---- O^T += V^T P^T : A[row = d = 16*mt + c][k = key = k0 + 8g + j] ----
        #pragma unroll
        for (int mt = 0; mt < 8; ++mt) {
            bf16x8 vf = *(const bf16x8*)(vbase + (size_t)(mt * 16 + c) * S_ + k0 + g * 8);
            acc[mt] = __builtin_amdgcn_mfma_f32_16x16x32_bf16(vf, pf, acc[mt], 0, 0, 0);
        }
    }

    // ---- epilogue: divide by row-sum, write out[b][q0+c][h][d] ----
    if (c == 0) {
        #pragma unroll
        for (int r = 0; r < 4; ++r) sm_stat[wave][4 * g + r] = l_run[r];
    }
    asm volatile("s_waitcnt lgkmcnt(0)" ::: "memory");
    float linv = 1.0f / sm_stat[wave][c];

    float* obase = out + ((size_t)b * S_ + (q0 + c)) * (H_ * D_) + h * D_;
    #pragma unroll
    for (int mt = 0; mt < 8; ++mt)
        #pragma unroll
        for (int r = 0; r < 4; ++r)
            obase[mt * 16 + 4 * g + r] = acc[mt][r] * linv;
}

// ---------------------------------------------------------------------------
extern "C" void kernel_launch(void* const* d_in, const int* in_sizes, int n_in,
                              void* d_out, int out_size, void* d_ws, size_t ws_size,
                              hipStream_t stream) {
    const float* q = (const float*)d_in[0];
    const float* k = (const float*)d_in[1];
    const float* v = (const float*)d_in[2];
    float* out = (float*)d_out;

    unsigned short* kbuf = (unsigned short*)d_ws;                       // 8 MB
    unsigned short* vbuf = kbuf + (size_t)B_ * KVH_ * S_ * D_;          // 8 MB

    convert_k<<<4096, 256, 0, stream>>>(k, kbuf);
    transpose_v<<<4096, 256, 0, stream>>>(v, vbuf);
    attn_fwd<<<2048, 256, 0, stream>>>(q, kbuf, vbuf, out);
}

// Round 2
// 213.729 us; speedup vs baseline: 4.2425x; 4.2425x over previous
//
#include <hip/hip_runtime.h>
#include <hip/hip_bf16.h>
#include <stdint.h>

#define B_    2
#define S_    2048
#define H_    32
#define KVH_  8
#define D_    128
#define NQT   16                 // S_/128 q-tiles
#define NBLK  (B_*H_*NQT)        // 1024 blocks

typedef __bf16 bf16x8 __attribute__((ext_vector_type(8)));
typedef unsigned short u16x8 __attribute__((ext_vector_type(8)));
typedef float f32x4 __attribute__((ext_vector_type(4)));

__device__ constexpr float SCALE_LOG2E = 0.08838834764831845f * 1.4426950408889634f;
__device__ constexpr float DEFER_RAW   = 62.0f;   // ~8/SCALE_LOG2E -> P <= 2^8

__device__ __forceinline__ unsigned short f2bf(float f) {
    unsigned int u = __builtin_bit_cast(unsigned int, f);
    u = (u + 0x7FFFu + ((u >> 16) & 1u)) >> 16;   // RNE
    return (unsigned short)u;
}

__device__ __forceinline__ void gload16(const unsigned short* gsrc, unsigned short* ldst) {
    __builtin_amdgcn_global_load_lds(
        (const __attribute__((address_space(1))) unsigned int*)gsrc,
        (__attribute__((address_space(3))) unsigned int*)ldst,
        16, 0, 0);
}

// ---------------------------------------------------------------------------
// Prepass 1: k [B,S,KVH,D] fp32 -> kbuf fragment-linear bf16.
// kbuf chunk layout: (((b*KVH+kvh)*128 + kb)*4 + ch)*64 + l, 8 elems/chunk:
//   value = K[b][s = kb*16 + (l&15)][kvh][d = ch*32 + (l>>4)*8 + j]
// ---------------------------------------------------------------------------
__global__ __launch_bounds__(256) void convert_k(const float* __restrict__ k,
                                                 unsigned short* __restrict__ kbuf) {
    int tid = blockIdx.x * 256 + threadIdx.x;   // 524288 total
    int l   = tid & 63;
    int ch  = (tid >> 6) & 3;
    int kb  = (tid >> 8) & 127;
    int kvh = (tid >> 15) & 7;
    int b   = tid >> 18;
    int s   = kb * 16 + (l & 15);
    int d0  = ch * 32 + (l >> 4) * 8;
    const float* src = k + (((size_t)b * S_ + s) * KVH_ + kvh) * D_ + d0;
    float4 x = ((const float4*)src)[0];
    float4 y = ((const float4*)src)[1];
    u16x8 o;
    o[0] = f2bf(x.x); o[1] = f2bf(x.y); o[2] = f2bf(x.z); o[3] = f2bf(x.w);
    o[4] = f2bf(y.x); o[5] = f2bf(y.y); o[6] = f2bf(y.z); o[7] = f2bf(y.w);
    *(u16x8*)(kbuf + ((size_t)(((b * KVH_ + kvh) * 128 + kb) * 4 + ch) * 64 + l) * 8) = o;
}

// ---------------------------------------------------------------------------
// Prepass 2: v [B,S,KVH,D] fp32 -> vbuf fragment-linear bf16 (V^T frags).
// vbuf chunk layout: (((b*KVH+kvh)*64 + vb)*8 + mt)*64 + l, 8 elems/chunk:
//   value = V[b][s = vb*32 + (l>>4)*8 + j][kvh][d = mt*16 + (l&15)]
// ---------------------------------------------------------------------------
__global__ __launch_bounds__(256) void transpose_v(const float* __restrict__ v,
                                                   unsigned short* __restrict__ vbuf) {
    __shared__ float tile[32][130];
    int bid = blockIdx.x;                  // 1024
    int vb  = bid & 63;
    int kvh = (bid >> 6) & 7;
    int b   = bid >> 9;
    int t   = threadIdx.x;

    int s   = t >> 3;
    int c16 = (t & 7) * 16;
    const float* src = v + (((size_t)b * S_ + vb * 32 + s) * KVH_ + kvh) * D_ + c16;
    #pragma unroll
    for (int j = 0; j < 4; ++j) {
        float4 x = ((const float4*)src)[j];
        tile[s][c16 + 4 * j + 0] = x.x; tile[s][c16 + 4 * j + 1] = x.y;
        tile[s][c16 + 4 * j + 2] = x.z; tile[s][c16 + 4 * j + 3] = x.w;
    }
    __syncthreads();

    #pragma unroll
    for (int i = 0; i < 2; ++i) {
        int ci = t + i * 256;              // 0..511
        int mt = ci >> 6, l = ci & 63, c = l & 15, g = l >> 4;
        u16x8 o;
        #pragma unroll
        for (int j = 0; j < 8; ++j) o[j] = f2bf(tile[g * 8 + j][mt * 16 + c]);
        *(u16x8*)(vbuf + ((size_t)(((b * KVH_ + kvh) * 64 + vb) * 8 + mt) * 64 + l) * 8) = o;
    }
}

// ---------------------------------------------------------------------------
// Main flash-attention kernel. 256 threads = 4 waves; block q-tile = 128 rows
// (wave owns 32 = two 16-row MFMA frags). KV tiles of 32 keys staged in LDS
// (double-buffered, global_load_lds), shared by all 4 waves.
// ---------------------------------------------------------------------------
__global__ __launch_bounds__(256, 2)
void attn_fwd(const float* __restrict__ q,
              const unsigned short* __restrict__ kbuf,
              const unsigned short* __restrict__ vbuf,
              float* __restrict__ out)
{
    // XCD-chunked swizzle (1024 % 8 == 0 -> bijective) + descending qtile
    int pid = blockIdx.x;
    int lid = (pid & 7) * (NBLK / 8) + (pid >> 3);
    int hg  = lid >> 6;                  // 0..15 = (b,kvh)
    int sub = lid & 63;
    int b   = hg >> 3, kvh = hg & 7;
    int h   = kvh * 4 + (sub >> 4);
    int qt  = 15 - (sub & 15);
    int qbase = qt * 128;

    const int tid = threadIdx.x, wave = tid >> 6, lane = tid & 63;
    const int c = lane & 15, g = lane >> 4;
    const int q0w = qbase + wave * 32;

    __shared__ __align__(16) unsigned short ldsK[2][4096];
    __shared__ __align__(16) unsigned short ldsV[2][4096];
    __shared__ __align__(16) unsigned short p_lds[4][2][16][40];
    __shared__ float sm_stat[4][32];

    const unsigned short* kfb = kbuf + (size_t)(b * KVH_ + kvh) * (S_ * D_);
    const unsigned short* vfb = vbuf + (size_t)(b * KVH_ + kvh) * (S_ * D_);

    // ---- Q fragments (2 m-frags x 4 k-chunks) ----
    bf16x8 qf[2][4];
    #pragma unroll
    for (int m = 0; m < 2; ++m) {
        const float* qp = q + ((size_t)b * S_ + q0w + m * 16 + c) * (H_ * D_) + h * D_ + g * 8;
        #pragma unroll
        for (int ch = 0; ch < 4; ++ch) {
            float4 a  = ((const float4*)(qp + ch * 32))[0];
            float4 bb = ((const float4*)(qp + ch * 32))[1];
            u16x8 tt;
            tt[0] = f2bf(a.x);  tt[1] = f2bf(a.y);  tt[2] = f2bf(a.z);  tt[3] = f2bf(a.w);
            tt[4] = f2bf(bb.x); tt[5] = f2bf(bb.y); tt[6] = f2bf(bb.z); tt[7] = f2bf(bb.w);
            qf[m][ch] = __builtin_bit_cast(bf16x8, tt);
        }
    }

    f32x4 acc[2][8];
    #pragma unroll
    for (int m = 0; m < 2; ++m)
        #pragma unroll
        for (int mt = 0; mt < 8; ++mt) acc[m][mt] = (f32x4){0.f, 0.f, 0.f, 0.f};
    float mrun[2][4], lsum[2][4];
    #pragma unroll
    for (int m = 0; m < 2; ++m)
        #pragma unroll
        for (int r = 0; r < 4; ++r) { mrun[m][r] = -INFINITY; lsum[m][r] = 0.f; }

    const int NT = 4 * qt + 4;

    // ---- stage one 32-key tile (K 8KB + V 8KB) into buf ----
    auto stage = [&](int t, int buf) {
        const unsigned short* ks = kfb + (size_t)t * 4096;
        const unsigned short* vs = vfb + (size_t)t * 4096;
        #pragma unroll
        for (int i = 0; i < 2; ++i) {
            int seg = wave * 2 + i;        // 0..7
            gload16(ks + seg * 512 + lane * 8, &ldsK[buf][seg * 512]);
            gload16(vs + seg * 512 + lane * 8, &ldsV[buf][seg * 512]);
        }
    };

    stage(0, 0);
    asm volatile("s_waitcnt vmcnt(0)" ::: "memory");
    __syncthreads();

    for (int it = 0; it < NT; ++it) {
        const int cur = it & 1;
        if (it + 1 < NT) stage(it + 1, cur ^ 1);
        const int k0 = it * 32;

        if (k0 <= q0w + 31) {
            // ---- K frags from LDS ----
            bf16x8 kf[2][4];
            #pragma unroll
            for (int t2 = 0; t2 < 2; ++t2)
                #pragma unroll
                for (int ch = 0; ch < 4; ++ch)
                    kf[t2][ch] = *(const bf16x8*)&ldsK[cur][(t2 * 4 + ch) * 512 + lane * 8];

            // ---- QK^T ----
            f32x4 sv[2][2];
            #pragma unroll
            for (int m = 0; m < 2; ++m)
                #pragma unroll
                for (int t2 = 0; t2 < 2; ++t2) sv[m][t2] = (f32x4){0.f, 0.f, 0.f, 0.f};
            __builtin_amdgcn_s_setprio(1);
            #pragma unroll
            for (int ch = 0; ch < 4; ++ch) {
                #pragma unroll
                for (int m = 0; m < 2; ++m) {
                    sv[m][0] = __builtin_amdgcn_mfma_f32_16x16x32_bf16(qf[m][ch], kf[0][ch], sv[m][0], 0, 0, 0);
                    sv[m][1] = __builtin_amdgcn_mfma_f32_16x16x32_bf16(qf[m][ch], kf[1][ch], sv[m][1], 0, 0, 0);
                }
            }
            __builtin_amdgcn_s_setprio(0);

            // ---- causal mask ----
            #pragma unroll
            for (int m = 0; m < 2; ++m) {
                if (k0 + 31 > q0w + m * 16) {
                    #pragma unroll
                    for (int t2 = 0; t2 < 2; ++t2)
                        #pragma unroll
                        for (int r = 0; r < 4; ++r)
                            if (k0 + 16 * t2 + c > q0w + m * 16 + 4 * g + r) sv[m][t2][r] = -INFINITY;
                }
            }

            // ---- defer-max online softmax ----
            float lm[2][4];
            bool ok = true;
            #pragma unroll
            for (int m = 0; m < 2; ++m)
                #pragma unroll
                for (int r = 0; r < 4; ++r) {
                    lm[m][r] = fmaxf(sv[m][0][r], sv[m][1][r]);
                    ok = ok && (lm[m][r] <= mrun[m][r] + DEFER_RAW);
                }

            if (!__all(ok)) {
                float mx[2][4];
                #pragma unroll
                for (int m = 0; m < 2; ++m)
                    #pragma unroll
                    for (int r = 0; r < 4; ++r) mx[m][r] = lm[m][r];
                #pragma unroll
                for (int off = 1; off < 16; off <<= 1)
                    #pragma unroll
                    for (int m = 0; m < 2; ++m)
                        #pragma unroll
                        for (int r = 0; r < 4; ++r)
                            mx[m][r] = fmaxf(mx[m][r], __shfl_xor(mx[m][r], off));
                float al[2][4];
                #pragma unroll
                for (int m = 0; m < 2; ++m)
                    #pragma unroll
                    for (int r = 0; r < 4; ++r) {
                        float mn = fmaxf(mrun[m][r], mx[m][r]);
                        al[m][r] = exp2f((mrun[m][r] - mn) * SCALE_LOG2E);
                        mrun[m][r] = mn;
                        lsum[m][r] *= al[m][r];
                    }
                if (c == 0) {
                    #pragma unroll
                    for (int m = 0; m < 2; ++m)
                        #pragma unroll
                        for (int r = 0; r < 4; ++r)
                            sm_stat[wave][m * 16 + 4 * g + r] = al[m][r];
                }
                asm volatile("s_waitcnt lgkmcnt(0)" ::: "memory");
                #pragma unroll
                for (int m = 0; m < 2; ++m) {
                    float ac = sm_stat[wave][m * 16 + c];
                    #pragma unroll
                    for (int mt = 0; mt < 8; ++mt) {
                        acc[m][mt][0] *= ac; acc[m][mt][1] *= ac;
                        acc[m][mt][2] *= ac; acc[m][mt][3] *= ac;
                    }
                }
            }

            // ---- P = exp2, per-lane partial sums, write P to LDS ----
            #pragma unroll
            for (int m = 0; m < 2; ++m)
                #pragma unroll
                for (int t2 = 0; t2 < 2; ++t2)
                    #pragma unroll
                    for (int r = 0; r < 4; ++r) {
                        float p = exp2f((sv[m][t2][r] - mrun[m][r]) * SCALE_LOG2E);
                        lsum[m][r] += p;
                        p_lds[wave][m][4 * g + r][16 * t2 + c] = f2bf(p);
                    }
            asm volatile("s_waitcnt lgkmcnt(0)" ::: "memory");

            bf16x8 pf[2];
            #pragma unroll
            for (int m = 0; m < 2; ++m)
                pf[m] = *(const bf16x8*)&p_lds[wave][m][c][g * 8];

            // ---- PV: O^T += V^T P^T ----
            __builtin_amdgcn_s_setprio(1);
            #pragma unroll
            for (int mt = 0; mt < 8; ++mt) {
                bf16x8 vf = *(const bf16x8*)&ldsV[cur][mt * 512 + lane * 8];
                acc[0][mt] = __builtin_amdgcn_mfma_f32_16x16x32_bf16(vf, pf[0], acc[0][mt], 0, 0, 0);
                acc[1][mt] = __builtin_amdgcn_mfma_f32_16x16x32_bf16(vf, pf[1], acc[1][mt], 0, 0, 0);
            }
            __builtin_amdgcn_s_setprio(0);
        }

        asm volatile("s_waitcnt vmcnt(0)" ::: "memory");
        __syncthreads();
    }

    // ---- epilogue: reduce per-lane partial sums once, normalize, store ----
    #pragma unroll
    for (int off = 1; off < 16; off <<= 1)
        #pragma unroll
        for (int m = 0; m < 2; ++m)
            #pragma unroll
            for (int r = 0; r < 4; ++r)
                lsum[m][r] += __shfl_xor(lsum[m][r], off);
    if (c == 0) {
        #pragma unroll
        for (int m = 0; m < 2; ++m)
            #pragma unroll
            for (int r = 0; r < 4; ++r)
                sm_stat[wave][m * 16 + 4 * g + r] = lsum[m][r];
    }
    asm volatile("s_waitcnt lgkmcnt(0)" ::: "memory");

    #pragma unroll
    for (int m = 0; m < 2; ++m) {
        float linv = 1.0f / sm_stat[wave][m * 16 + c];
        float* ob = out + ((size_t)b * S_ + q0w + m * 16 + c) * (H_ * D_) + h * D_;
        #pragma unroll
        for (int mt = 0; mt < 8; ++mt) {
            float4 o;
            o.x = acc[m][mt][0] * linv; o.y = acc[m][mt][1] * linv;
            o.z = acc[m][mt][2] * linv; o.w = acc[m][mt][3] * linv;
            *(float4*)(ob + mt * 16 + 4 * g) = o;
        }
    }
}

// ---------------------------------------------------------------------------
extern "C" void kernel_launch(void* const* d_in, const int* in_sizes, int n_in,
                              void* d_out, int out_size, void* d_ws, size_t ws_size,
                              hipStream_t stream) {
    const float* q = (const float*)d_in[0];
    const float* k = (const float*)d_in[1];
    const float* v = (const float*)d_in[2];
    float* out = (float*)d_out;

    unsigned short* kbuf = (unsigned short*)d_ws;                       // 8 MB
    unsigned short* vbuf = kbuf + (size_t)B_ * KVH_ * S_ * D_;          // 8 MB

    convert_k<<<2048, 256, 0, stream>>>(k, kbuf);
    transpose_v<<<1024, 256, 0, stream>>>(v, vbuf);
    attn_fwd<<<NBLK, 256, 0, stream>>>(q, kbuf, vbuf, out);
}

// Round 3
// 157.728 us; speedup vs baseline: 5.7488x; 1.3550x over previous
//
#include <hip/hip_runtime.h>
#include <hip/hip_bf16.h>
#include <stdint.h>

#define B_    2
#define S_    2048
#define H_    32
#define KVH_  8
#define D_    128
#define NBLK  512                // (B*H)=64 bh-pairs x 8 qtile-pairs
#define NTOT  68                 // 4*qtA+4 + 4*qtB+4 with qtA+qtB=15 (uniform!)

typedef __bf16 bf16x8 __attribute__((ext_vector_type(8)));
typedef unsigned short u16x8 __attribute__((ext_vector_type(8)));
typedef float f32x4 __attribute__((ext_vector_type(4)));

// softmax scale * log2(e), folded into Q at fragment load -> scores in log2 domain
__device__ constexpr float SCALE_LOG2E = 0.08838834764831845f * 1.4426950408889634f;
__device__ constexpr float DEFER_LOG2  = 11.0f;   // defer-max threshold: P <= 2^11

__device__ __forceinline__ unsigned short f2bf(float f) {
    unsigned int u = __builtin_bit_cast(unsigned int, f);
    u = (u + 0x7FFFu + ((u >> 16) & 1u)) >> 16;   // RNE
    return (unsigned short)u;
}

__device__ __forceinline__ void gload16(const unsigned short* gsrc, unsigned short* ldst) {
    __builtin_amdgcn_global_load_lds(
        (const __attribute__((address_space(1))) unsigned int*)gsrc,
        (__attribute__((address_space(3))) unsigned int*)ldst,
        16, 0, 0);
}

// ---------------------------------------------------------------------------
// Prepass 1: k [B,S,KVH,D] fp32 -> kbuf fragment-linear bf16.
// chunk ((((b*KVH+kvh)*128 + kb)*4 + ch)*64 + l)*8 :
//   K[b][s = kb*16 + (l&15)][kvh][d = ch*32 + (l>>4)*8 + j]
// ---------------------------------------------------------------------------
__global__ __launch_bounds__(256) void convert_k(const float* __restrict__ k,
                                                 unsigned short* __restrict__ kbuf) {
    int tid = blockIdx.x * 256 + threadIdx.x;
    int l   = tid & 63;
    int ch  = (tid >> 6) & 3;
    int kb  = (tid >> 8) & 127;
    int kvh = (tid >> 15) & 7;
    int b   = tid >> 18;
    int s   = kb * 16 + (l & 15);
    int d0  = ch * 32 + (l >> 4) * 8;
    const float* src = k + (((size_t)b * S_ + s) * KVH_ + kvh) * D_ + d0;
    float4 x = ((const float4*)src)[0];
    float4 y = ((const float4*)src)[1];
    u16x8 o;
    o[0] = f2bf(x.x); o[1] = f2bf(x.y); o[2] = f2bf(x.z); o[3] = f2bf(x.w);
    o[4] = f2bf(y.x); o[5] = f2bf(y.y); o[6] = f2bf(y.z); o[7] = f2bf(y.w);
    *(u16x8*)(kbuf + ((size_t)(((b * KVH_ + kvh) * 128 + kb) * 4 + ch) * 64 + l) * 8) = o;
}

// ---------------------------------------------------------------------------
// Prepass 2: v [B,S,KVH,D] fp32 -> vbuf fragment-linear bf16 (V^T frags).
// chunk ((((b*KVH+kvh)*64 + vb)*8 + mt)*64 + l)*8 :
//   V[b][s = vb*32 + (l>>4)*8 + j][kvh][d = mt*16 + (l&15)]
// ---------------------------------------------------------------------------
__global__ __launch_bounds__(256) void transpose_v(const float* __restrict__ v,
                                                   unsigned short* __restrict__ vbuf) {
    __shared__ float tile[32][130];
    int bid = blockIdx.x;                  // 1024
    int vb  = bid & 63;
    int kvh = (bid >> 6) & 7;
    int b   = bid >> 9;
    int t   = threadIdx.x;

    int s   = t >> 3;
    int c16 = (t & 7) * 16;
    const float* src = v + (((size_t)b * S_ + vb * 32 + s) * KVH_ + kvh) * D_ + c16;
    #pragma unroll
    for (int j = 0; j < 4; ++j) {
        float4 x = ((const float4*)src)[j];
        tile[s][c16 + 4 * j + 0] = x.x; tile[s][c16 + 4 * j + 1] = x.y;
        tile[s][c16 + 4 * j + 2] = x.z; tile[s][c16 + 4 * j + 3] = x.w;
    }
    __syncthreads();

    #pragma unroll
    for (int i = 0; i < 2; ++i) {
        int ci = t + i * 256;
        int mt = ci >> 6, l = ci & 63, c = l & 15, g = l >> 4;
        u16x8 o;
        #pragma unroll
        for (int j = 0; j < 8; ++j) o[j] = f2bf(tile[g * 8 + j][mt * 16 + c]);
        *(u16x8*)(vbuf + ((size_t)(((b * KVH_ + kvh) * 64 + vb) * 8 + mt) * 64 + l) * 8) = o;
    }
}

// ---------------------------------------------------------------------------
// Main kernel: 256 threads = 4 waves. Block processes TWO 128-row q-tiles
// (qt, 15-qt) -> uniform 68 KV-iterations per block (perfect balance).
// KV staged in LDS via global_load_lds, TRIPLE-buffered, counted vmcnt(4)
// (never drain to 0 in the loop), raw s_barrier.
// ---------------------------------------------------------------------------
__global__ __launch_bounds__(256, 2)
void attn_fwd(const float* __restrict__ q,
              const unsigned short* __restrict__ kbuf,
              const unsigned short* __restrict__ vbuf,
              float* __restrict__ out)
{
    // XCD-chunked swizzle (512 % 8 == 0 -> bijective)
    int pid = blockIdx.x;
    int lid = (pid & 7) * (NBLK / 8) + (pid >> 3);
    int p   = lid & 7;                    // q-tile pair index
    int bh  = lid >> 3;
    int b   = bh >> 5, h = bh & 31, kvh = h >> 2;
    const int qtA = 15 - p;               // long tile first
    const int NTA = 4 * qtA + 4;
    const int qtB = p;

    const int tid = threadIdx.x, wave = tid >> 6, lane = tid & 63;
    const int c = lane & 15, g = lane >> 4;

    __shared__ __align__(16) unsigned short ldsK[3][4096];
    __shared__ __align__(16) unsigned short ldsV[3][4096];
    __shared__ __align__(16) unsigned short p_lds[4][2][16][40];
    __shared__ float sm_stat[4][32];

    const unsigned short* kfb = kbuf + (size_t)(b * KVH_ + kvh) * (S_ * D_);
    const unsigned short* vfb = vbuf + (size_t)(b * KVH_ + kvh) * (S_ * D_);

    // stage global KV iter u (maps through the two-tile schedule; same KV data)
    auto stage = [&](int u) {
        int t = (u < NTA) ? u : (u - NTA);
        const unsigned short* ks = kfb + (size_t)t * 4096;
        const unsigned short* vs = vfb + (size_t)t * 4096;
        int buf = u % 3;
        #pragma unroll
        for (int i = 0; i < 2; ++i) {
            int seg = wave * 2 + i;
            gload16(ks + seg * 512 + lane * 8, &ldsK[buf][seg * 512]);
            gload16(vs + seg * 512 + lane * 8, &ldsV[buf][seg * 512]);
        }
    };

    stage(0);
    stage(1);
    asm volatile("s_waitcnt vmcnt(4)" ::: "memory");   // stage(0) landed
    __builtin_amdgcn_s_barrier();
    asm volatile("" ::: "memory");

    auto run_tile = [&](int qt, int u0, int NT) {
        const int q0w = qt * 128 + wave * 32;

        // Q fragments, scale*log2e folded
        bf16x8 qf[2][4];
        #pragma unroll
        for (int m = 0; m < 2; ++m) {
            const float* qp = q + ((size_t)b * S_ + q0w + m * 16 + c) * (H_ * D_) + h * D_ + g * 8;
            #pragma unroll
            for (int ch = 0; ch < 4; ++ch) {
                float4 a  = ((const float4*)(qp + ch * 32))[0];
                float4 bb = ((const float4*)(qp + ch * 32))[1];
                u16x8 tt;
                tt[0] = f2bf(a.x * SCALE_LOG2E);  tt[1] = f2bf(a.y * SCALE_LOG2E);
                tt[2] = f2bf(a.z * SCALE_LOG2E);  tt[3] = f2bf(a.w * SCALE_LOG2E);
                tt[4] = f2bf(bb.x * SCALE_LOG2E); tt[5] = f2bf(bb.y * SCALE_LOG2E);
                tt[6] = f2bf(bb.z * SCALE_LOG2E); tt[7] = f2bf(bb.w * SCALE_LOG2E);
                qf[m][ch] = __builtin_bit_cast(bf16x8, tt);
            }
        }

        f32x4 acc[2][8];
        #pragma unroll
        for (int m = 0; m < 2; ++m)
            #pragma unroll
            for (int mt = 0; mt < 8; ++mt) acc[m][mt] = (f32x4){0.f, 0.f, 0.f, 0.f};
        float mrun[2][4], lsum[2][4];
        #pragma unroll
        for (int m = 0; m < 2; ++m)
            #pragma unroll
            for (int r = 0; r < 4; ++r) { mrun[m][r] = -INFINITY; lsum[m][r] = 0.f; }

        for (int it = 0; it < NT; ++it) {
            const int u = u0 + it;
            if (u + 2 < NTOT) stage(u + 2);
            const int cur = u % 3;
            const int k0 = it * 32;

            if (k0 <= q0w + 31) {
                bf16x8 kf[2][4];
                #pragma unroll
                for (int t2 = 0; t2 < 2; ++t2)
                    #pragma unroll
                    for (int ch = 0; ch < 4; ++ch)
                        kf[t2][ch] = *(const bf16x8*)&ldsK[cur][(t2 * 4 + ch) * 512 + lane * 8];

                f32x4 sv[2][2];
                #pragma unroll
                for (int m = 0; m < 2; ++m)
                    #pragma unroll
                    for (int t2 = 0; t2 < 2; ++t2) sv[m][t2] = (f32x4){0.f, 0.f, 0.f, 0.f};
                __builtin_amdgcn_s_setprio(1);
                #pragma unroll
                for (int ch = 0; ch < 4; ++ch) {
                    #pragma unroll
                    for (int m = 0; m < 2; ++m) {
                        sv[m][0] = __builtin_amdgcn_mfma_f32_16x16x32_bf16(qf[m][ch], kf[0][ch], sv[m][0], 0, 0, 0);
                        sv[m][1] = __builtin_amdgcn_mfma_f32_16x16x32_bf16(qf[m][ch], kf[1][ch], sv[m][1], 0, 0, 0);
                    }
                }
                __builtin_amdgcn_s_setprio(0);

                // causal mask
                #pragma unroll
                for (int m = 0; m < 2; ++m) {
                    if (k0 + 31 > q0w + m * 16) {
                        #pragma unroll
                        for (int t2 = 0; t2 < 2; ++t2)
                            #pragma unroll
                            for (int r = 0; r < 4; ++r)
                                if (k0 + 16 * t2 + c > q0w + m * 16 + 4 * g + r) sv[m][t2][r] = -INFINITY;
                    }
                }

                // defer-max online softmax (log2 domain)
                float lm[2][4];
                bool ok = true;
                #pragma unroll
                for (int m = 0; m < 2; ++m)
                    #pragma unroll
                    for (int r = 0; r < 4; ++r) {
                        lm[m][r] = fmaxf(sv[m][0][r], sv[m][1][r]);
                        ok = ok && (lm[m][r] <= mrun[m][r] + DEFER_LOG2);
                    }

                if (!__all(ok)) {
                    float mx[2][4];
                    #pragma unroll
                    for (int m = 0; m < 2; ++m)
                        #pragma unroll
                        for (int r = 0; r < 4; ++r) mx[m][r] = lm[m][r];
                    #pragma unroll
                    for (int off = 1; off < 16; off <<= 1)
                        #pragma unroll
                        for (int m = 0; m < 2; ++m)
                            #pragma unroll
                            for (int r = 0; r < 4; ++r)
                                mx[m][r] = fmaxf(mx[m][r], __shfl_xor(mx[m][r], off));
                    float al[2][4];
                    #pragma unroll
                    for (int m = 0; m < 2; ++m)
                        #pragma unroll
                        for (int r = 0; r < 4; ++r) {
                            float mn = fmaxf(mrun[m][r], mx[m][r]);
                            al[m][r] = exp2f(mrun[m][r] - mn);
                            mrun[m][r] = mn;
                            lsum[m][r] *= al[m][r];
                        }
                    if (c == 0) {
                        #pragma unroll
                        for (int m = 0; m < 2; ++m)
                            #pragma unroll
                            for (int r = 0; r < 4; ++r)
                                sm_stat[wave][m * 16 + 4 * g + r] = al[m][r];
                    }
                    asm volatile("s_waitcnt lgkmcnt(0)" ::: "memory");
                    #pragma unroll
                    for (int m = 0; m < 2; ++m) {
                        float ac = sm_stat[wave][m * 16 + c];
                        #pragma unroll
                        for (int mt = 0; mt < 8; ++mt) {
                            acc[m][mt][0] *= ac; acc[m][mt][1] *= ac;
                            acc[m][mt][2] *= ac; acc[m][mt][3] *= ac;
                        }
                    }
                }

                // P = exp2(S - m), per-lane partial row-sums, P -> LDS
                #pragma unroll
                for (int m = 0; m < 2; ++m)
                    #pragma unroll
                    for (int t2 = 0; t2 < 2; ++t2)
                        #pragma unroll
                        for (int r = 0; r < 4; ++r) {
                            float pv = exp2f(sv[m][t2][r] - mrun[m][r]);
                            lsum[m][r] += pv;
                            p_lds[wave][m][4 * g + r][16 * t2 + c] = f2bf(pv);
                        }
                asm volatile("s_waitcnt lgkmcnt(0)" ::: "memory");

                bf16x8 pf[2];
                #pragma unroll
                for (int m = 0; m < 2; ++m)
                    pf[m] = *(const bf16x8*)&p_lds[wave][m][c][g * 8];

                __builtin_amdgcn_s_setprio(1);
                #pragma unroll
                for (int mt = 0; mt < 8; ++mt) {
                    bf16x8 vf = *(const bf16x8*)&ldsV[cur][mt * 512 + lane * 8];
                    acc[0][mt] = __builtin_amdgcn_mfma_f32_16x16x32_bf16(vf, pf[0], acc[0][mt], 0, 0, 0);
                    acc[1][mt] = __builtin_amdgcn_mfma_f32_16x16x32_bf16(vf, pf[1], acc[1][mt], 0, 0, 0);
                }
                __builtin_amdgcn_s_setprio(0);
            }

            // counted-vmcnt pipeline: wait only for stage(u+1); keep stage(u+2) in flight
            if (u + 2 < NTOT) {
                asm volatile("s_waitcnt vmcnt(4)" ::: "memory");
                __builtin_amdgcn_s_barrier();
                asm volatile("" ::: "memory");
            } else if (u + 1 < NTOT) {
                asm volatile("s_waitcnt vmcnt(0)" ::: "memory");
                __builtin_amdgcn_s_barrier();
                asm volatile("" ::: "memory");
            }
        }

        // epilogue: reduce row-sums, normalize, store
        #pragma unroll
        for (int off = 1; off < 16; off <<= 1)
            #pragma unroll
            for (int m = 0; m < 2; ++m)
                #pragma unroll
                for (int r = 0; r < 4; ++r)
                    lsum[m][r] += __shfl_xor(lsum[m][r], off);
        if (c == 0) {
            #pragma unroll
            for (int m = 0; m < 2; ++m)
                #pragma unroll
                for (int r = 0; r < 4; ++r)
                    sm_stat[wave][m * 16 + 4 * g + r] = lsum[m][r];
        }
        asm volatile("s_waitcnt lgkmcnt(0)" ::: "memory");

        #pragma unroll
        for (int m = 0; m < 2; ++m) {
            float linv = 1.0f / sm_stat[wave][m * 16 + c];
            float* ob = out + ((size_t)b * S_ + q0w + m * 16 + c) * (H_ * D_) + h * D_;
            #pragma unroll
            for (int mt = 0; mt < 8; ++mt) {
                float4 o;
                o.x = acc[m][mt][0] * linv; o.y = acc[m][mt][1] * linv;
                o.z = acc[m][mt][2] * linv; o.w = acc[m][mt][3] * linv;
                *(float4*)(ob + mt * 16 + 4 * g) = o;
            }
        }
    };

    run_tile(qtA, 0, NTA);
    run_tile(qtB, NTA, NTOT - NTA);
}

// ---------------------------------------------------------------------------
extern "C" void kernel_launch(void* const* d_in, const int* in_sizes, int n_in,
                              void* d_out, int out_size, void* d_ws, size_t ws_size,
                              hipStream_t stream) {
    const float* q = (const float*)d_in[0];
    const float* k = (const float*)d_in[1];
    const float* v = (const float*)d_in[2];
    float* out = (float*)d_out;

    unsigned short* kbuf = (unsigned short*)d_ws;                       // 8 MB
    unsigned short* vbuf = kbuf + (size_t)B_ * KVH_ * S_ * D_;          // 8 MB

    convert_k<<<2048, 256, 0, stream>>>(k, kbuf);
    transpose_v<<<1024, 256, 0, stream>>>(v, vbuf);
    attn_fwd<<<NBLK, 256, 0, stream>>>(q, kbuf, vbuf, out);
}

// Round 4
// 142.133 us; speedup vs baseline: 6.3796x; 1.1097x over previous
//
#include <hip/hip_runtime.h>
#include <hip/hip_bf16.h>
#include <stdint.h>

#define B_    2
#define S_    2048
#define H_    32
#define KVH_  8
#define D_    128
#define NBLK  512                // (B*H)=64 bh-pairs x 8 qtile-pairs
#define NTOT  68                 // 4*qtA+4 + 4*qtB+4 with qtA+qtB=15 (uniform)

typedef __bf16 bf16x8 __attribute__((ext_vector_type(8)));
typedef unsigned short u16x8 __attribute__((ext_vector_type(8)));
typedef unsigned int u32x4 __attribute__((ext_vector_type(4)));
typedef float f32x4 __attribute__((ext_vector_type(4)));

// softmax scale * log2(e), folded into Q at fragment load -> scores in log2 domain
__device__ constexpr float SCALE_LOG2E = 0.08838834764831845f * 1.4426950408889634f;
__device__ constexpr float DEFER_LOG2  = 11.0f;   // defer-max threshold: P <= 2^11

__device__ __forceinline__ unsigned short f2bf(float f) {
    unsigned int u = __builtin_bit_cast(unsigned int, f);
    u = (u + 0x7FFFu + ((u >> 16) & 1u)) >> 16;   // RNE
    return (unsigned short)u;
}

__device__ __forceinline__ unsigned int cvt_pk_bf16(float lo, float hi) {
    unsigned int r;
    asm("v_cvt_pk_bf16_f32 %0, %1, %2" : "=v"(r) : "v"(lo), "v"(hi));
    return r;
}

__device__ __forceinline__ void gload16(const unsigned short* gsrc, unsigned short* ldst) {
    __builtin_amdgcn_global_load_lds(
        (const __attribute__((address_space(1))) unsigned int*)gsrc,
        (__attribute__((address_space(3))) unsigned int*)ldst,
        16, 0, 0);
}

// ---------------------------------------------------------------------------
// Merged prepass. Blocks 0..2047: K -> fragment-linear bf16.
//   kbuf chunk ((((b*KVH+kvh)*128 + kb)*4 + ch)*64 + l)*8 :
//     K[b][s = kb*16 + (l&15)][kvh][d = ch*32 + (l>>4)*8 + j]
// Blocks 2048..3071: V -> fragment-linear bf16 (V^T frags).
//   vbuf chunk ((((b*KVH+kvh)*64 + vb)*8 + mt)*64 + l)*8 :
//     V[b][s = vb*32 + (l>>4)*8 + j][kvh][d = mt*16 + (l&15)]
// ---------------------------------------------------------------------------
__global__ __launch_bounds__(256) void prepass(const float* __restrict__ k,
                                               const float* __restrict__ v,
                                               unsigned short* __restrict__ kbuf,
                                               unsigned short* __restrict__ vbuf) {
    if (blockIdx.x < 2048) {
        int tid = blockIdx.x * 256 + threadIdx.x;
        int l   = tid & 63;
        int ch  = (tid >> 6) & 3;
        int kb  = (tid >> 8) & 127;
        int kvh = (tid >> 15) & 7;
        int b   = tid >> 18;
        int s   = kb * 16 + (l & 15);
        int d0  = ch * 32 + (l >> 4) * 8;
        const float* src = k + (((size_t)b * S_ + s) * KVH_ + kvh) * D_ + d0;
        float4 x = ((const float4*)src)[0];
        float4 y = ((const float4*)src)[1];
        u16x8 o;
        o[0] = f2bf(x.x); o[1] = f2bf(x.y); o[2] = f2bf(x.z); o[3] = f2bf(x.w);
        o[4] = f2bf(y.x); o[5] = f2bf(y.y); o[6] = f2bf(y.z); o[7] = f2bf(y.w);
        *(u16x8*)(kbuf + ((size_t)(((b * KVH_ + kvh) * 128 + kb) * 4 + ch) * 64 + l) * 8) = o;
    } else {
        __shared__ float tile[32][130];
        int bid = blockIdx.x - 2048;           // 0..1023
        int vb  = bid & 63;
        int kvh = (bid >> 6) & 7;
        int b   = bid >> 9;
        int t   = threadIdx.x;

        int s   = t >> 3;
        int c16 = (t & 7) * 16;
        const float* src = v + (((size_t)b * S_ + vb * 32 + s) * KVH_ + kvh) * D_ + c16;
        #pragma unroll
        for (int j = 0; j < 4; ++j) {
            float4 x = ((const float4*)src)[j];
            tile[s][c16 + 4 * j + 0] = x.x; tile[s][c16 + 4 * j + 1] = x.y;
            tile[s][c16 + 4 * j + 2] = x.z; tile[s][c16 + 4 * j + 3] = x.w;
        }
        __syncthreads();

        #pragma unroll
        for (int i = 0; i < 2; ++i) {
            int ci = t + i * 256;
            int mt = ci >> 6, l = ci & 63, c = l & 15, g = l >> 4;
            u16x8 o;
            #pragma unroll
            for (int j = 0; j < 8; ++j) o[j] = f2bf(tile[g * 8 + j][mt * 16 + c]);
            *(u16x8*)(vbuf + ((size_t)(((b * KVH_ + kvh) * 64 + vb) * 8 + mt) * 64 + l) * 8) = o;
        }
    }
}

// ---------------------------------------------------------------------------
// Main kernel: 256 threads = 4 waves; block runs TWO 128-row q-tiles
// (qt, 15-qt) -> uniform 68 KV-iterations. KV triple-buffered in LDS via
// global_load_lds + counted vmcnt(4). SWAPPED QK^T (mfma(K,Q)) makes softmax
// stats lane-local per q-column: no P-LDS round trip, no stat broadcasts.
// ---------------------------------------------------------------------------
__global__ __launch_bounds__(256, 2)
void attn_fwd(const float* __restrict__ q,
              const unsigned short* __restrict__ kbuf,
              const unsigned short* __restrict__ vbuf,
              float* __restrict__ out)
{
    // XCD-chunked swizzle (512 % 8 == 0 -> bijective)
    int pid = blockIdx.x;
    int lid = (pid & 7) * (NBLK / 8) + (pid >> 3);
    int p   = lid & 7;                    // q-tile pair index
    int bh  = lid >> 3;
    int b   = bh >> 5, h = bh & 31, kvh = h >> 2;
    const int qtA = 15 - p;               // long tile first
    const int NTA = 4 * qtA + 4;
    const int qtB = p;

    const int tid = threadIdx.x, wave = tid >> 6, lane = tid & 63;
    const int c = lane & 15, g = lane >> 4;

    __shared__ __align__(16) unsigned short ldsK[3][4096];
    __shared__ __align__(16) unsigned short ldsV[3][4096];

    const unsigned short* kfb = kbuf + (size_t)(b * KVH_ + kvh) * (S_ * D_);
    const unsigned short* vfb = vbuf + (size_t)(b * KVH_ + kvh) * (S_ * D_);

    // bpermute source-lane byte addresses for the P redistribution
    const int addr0 = (c + 16 * ((2 * g) & 3)) * 4;        // for out words s=0,1
    const int addr1 = (c + 16 * ((2 * g + 1) & 3)) * 4;    // for out words s=2,3
    const bool ghi = (g >= 2);

    auto stage = [&](int u) {
        int t = (u < NTA) ? u : (u - NTA);
        const unsigned short* ks = kfb + (size_t)t * 4096;
        const unsigned short* vs = vfb + (size_t)t * 4096;
        int buf = u % 3;
        #pragma unroll
        for (int i = 0; i < 2; ++i) {
            int seg = wave * 2 + i;
            gload16(ks + seg * 512 + lane * 8, &ldsK[buf][seg * 512]);
            gload16(vs + seg * 512 + lane * 8, &ldsV[buf][seg * 512]);
        }
    };

    stage(0);
    stage(1);
    asm volatile("s_waitcnt vmcnt(4)" ::: "memory");   // stage(0) landed
    __builtin_amdgcn_s_barrier();
    asm volatile("" ::: "memory");

    auto run_tile = [&](int qt, int u0, int NT) {
        const int q0w = qt * 128 + wave * 32;

        // Q fragments (B-operand), scale*log2e folded
        bf16x8 qf[2][4];
        #pragma unroll
        for (int m = 0; m < 2; ++m) {
            const float* qp = q + ((size_t)b * S_ + q0w + m * 16 + c) * (H_ * D_) + h * D_ + g * 8;
            #pragma unroll
            for (int ch = 0; ch < 4; ++ch) {
                float4 a  = ((const float4*)(qp + ch * 32))[0];
                float4 bb = ((const float4*)(qp + ch * 32))[1];
                u16x8 tt;
                tt[0] = f2bf(a.x * SCALE_LOG2E);  tt[1] = f2bf(a.y * SCALE_LOG2E);
                tt[2] = f2bf(a.z * SCALE_LOG2E);  tt[3] = f2bf(a.w * SCALE_LOG2E);
                tt[4] = f2bf(bb.x * SCALE_LOG2E); tt[5] = f2bf(bb.y * SCALE_LOG2E);
                tt[6] = f2bf(bb.z * SCALE_LOG2E); tt[7] = f2bf(bb.w * SCALE_LOG2E);
                qf[m][ch] = __builtin_bit_cast(bf16x8, tt);
            }
        }

        f32x4 acc[2][8];
        #pragma unroll
        for (int m = 0; m < 2; ++m)
            #pragma unroll
            for (int mt = 0; mt < 8; ++mt) acc[m][mt] = (f32x4){0.f, 0.f, 0.f, 0.f};
        float mrun[2], lsum[2];
        #pragma unroll
        for (int m = 0; m < 2; ++m) { mrun[m] = -INFINITY; lsum[m] = 0.f; }

        for (int it = 0; it < NT; ++it) {
            const int u = u0 + it;
            if (u + 2 < NTOT) stage(u + 2);
            const int cur = u % 3;
            const int k0 = it * 32;

            if (k0 <= q0w + 31) {
                bf16x8 kf[2][4];
                #pragma unroll
                for (int t2 = 0; t2 < 2; ++t2)
                    #pragma unroll
                    for (int ch = 0; ch < 4; ++ch)
                        kf[t2][ch] = *(const bf16x8*)&ldsK[cur][(t2 * 4 + ch) * 512 + lane * 8];

                // ---- SWAPPED QK^T: sv[m][t2][r] = S[key = k0+16*t2+4g+r][q = q0w+16m+c]
                f32x4 sv[2][2];
                #pragma unroll
                for (int m = 0; m < 2; ++m)
                    #pragma unroll
                    for (int t2 = 0; t2 < 2; ++t2) sv[m][t2] = (f32x4){0.f, 0.f, 0.f, 0.f};
                __builtin_amdgcn_s_setprio(1);
                #pragma unroll
                for (int ch = 0; ch < 4; ++ch) {
                    #pragma unroll
                    for (int m = 0; m < 2; ++m) {
                        sv[m][0] = __builtin_amdgcn_mfma_f32_16x16x32_bf16(kf[0][ch], qf[m][ch], sv[m][0], 0, 0, 0);
                        sv[m][1] = __builtin_amdgcn_mfma_f32_16x16x32_bf16(kf[1][ch], qf[m][ch], sv[m][1], 0, 0, 0);
                    }
                }
                __builtin_amdgcn_s_setprio(0);

                // causal mask: key = k0+16t2+4g+r vs q = q0w+16m+c
                #pragma unroll
                for (int m = 0; m < 2; ++m) {
                    if (k0 + 31 > q0w + m * 16) {
                        #pragma unroll
                        for (int t2 = 0; t2 < 2; ++t2)
                            #pragma unroll
                            for (int r = 0; r < 4; ++r)
                                if (k0 + 16 * t2 + 4 * g + r > q0w + m * 16 + c) sv[m][t2][r] = -INFINITY;
                    }
                }

                // ---- defer-max online softmax (stats per q-column, lane-local) ----
                float lm[2];
                #pragma unroll
                for (int m = 0; m < 2; ++m) {
                    float a0 = fmaxf(fmaxf(sv[m][0][0], sv[m][0][1]), fmaxf(sv[m][0][2], sv[m][0][3]));
                    float a1 = fmaxf(fmaxf(sv[m][1][0], sv[m][1][1]), fmaxf(sv[m][1][2], sv[m][1][3]));
                    lm[m] = fmaxf(a0, a1);
                }
                bool ok = (lm[0] <= mrun[0] + DEFER_LOG2) && (lm[1] <= mrun[1] + DEFER_LOG2);

                if (!__all(ok)) {
                    #pragma unroll
                    for (int m = 0; m < 2; ++m) {
                        float mx = lm[m];
                        mx = fmaxf(mx, __shfl_xor(mx, 16));
                        mx = fmaxf(mx, __shfl_xor(mx, 32));   // column max (all 4 g-lanes agree)
                        float mn = fmaxf(mrun[m], mx);
                        float al = exp2f(mrun[m] - mn);
                        mrun[m] = mn;
                        lsum[m] *= al;
                        #pragma unroll
                        for (int mt = 0; mt < 8; ++mt) {
                            acc[m][mt][0] *= al; acc[m][mt][1] *= al;
                            acc[m][mt][2] *= al; acc[m][mt][3] *= al;
                        }
                    }
                }

                // ---- P = exp2(S - m); per-lane partial sums; pack bf16 pairs ----
                bf16x8 pf[2];
                #pragma unroll
                for (int m = 0; m < 2; ++m) {
                    float pv[2][4];
                    #pragma unroll
                    for (int t2 = 0; t2 < 2; ++t2)
                        #pragma unroll
                        for (int r = 0; r < 4; ++r) {
                            pv[t2][r] = exp2f(sv[m][t2][r] - mrun[m]);
                        }
                    lsum[m] += ((pv[0][0] + pv[0][1]) + (pv[0][2] + pv[0][3]))
                             + ((pv[1][0] + pv[1][1]) + (pv[1][2] + pv[1][3]));
                    // w[t2][rr]: keys 16t2+4g+2rr..+1 for column c
                    unsigned int w00 = cvt_pk_bf16(pv[0][0], pv[0][1]);
                    unsigned int w01 = cvt_pk_bf16(pv[0][2], pv[0][3]);
                    unsigned int w10 = cvt_pk_bf16(pv[1][0], pv[1][1]);
                    unsigned int w11 = cvt_pk_bf16(pv[1][2], pv[1][3]);
                    // redistribute: out word s holds keys 8g+2s..+1, pulled from
                    // lane (c, (2g+(s>>1))&3), word (t2'=g>>1, rr'=s&1)
                    u32x4 W;
                    {
                        int a0w0 = __builtin_amdgcn_ds_bpermute(addr0, (int)w00);
                        int a0w1 = __builtin_amdgcn_ds_bpermute(addr0, (int)w10);
                        W[0] = (unsigned int)(ghi ? a0w1 : a0w0);
                        int b0w0 = __builtin_amdgcn_ds_bpermute(addr0, (int)w01);
                        int b0w1 = __builtin_amdgcn_ds_bpermute(addr0, (int)w11);
                        W[1] = (unsigned int)(ghi ? b0w1 : b0w0);
                        int a1w0 = __builtin_amdgcn_ds_bpermute(addr1, (int)w00);
                        int a1w1 = __builtin_amdgcn_ds_bpermute(addr1, (int)w10);
                        W[2] = (unsigned int)(ghi ? a1w1 : a1w0);
                        int b1w0 = __builtin_amdgcn_ds_bpermute(addr1, (int)w01);
                        int b1w1 = __builtin_amdgcn_ds_bpermute(addr1, (int)w11);
                        W[3] = (unsigned int)(ghi ? b1w1 : b1w0);
                    }
                    pf[m] = __builtin_bit_cast(bf16x8, W);
                }

                // ---- PV: O^T += V^T P^T ----
                __builtin_amdgcn_s_setprio(1);
                #pragma unroll
                for (int mt = 0; mt < 8; ++mt) {
                    bf16x8 vf = *(const bf16x8*)&ldsV[cur][mt * 512 + lane * 8];
                    acc[0][mt] = __builtin_amdgcn_mfma_f32_16x16x32_bf16(vf, pf[0], acc[0][mt], 0, 0, 0);
                    acc[1][mt] = __builtin_amdgcn_mfma_f32_16x16x32_bf16(vf, pf[1], acc[1][mt], 0, 0, 0);
                }
                __builtin_amdgcn_s_setprio(0);
            }

            // counted-vmcnt pipeline: wait only for stage(u+1); keep stage(u+2) in flight
            if (u + 2 < NTOT) {
                asm volatile("s_waitcnt vmcnt(4)" ::: "memory");
                __builtin_amdgcn_s_barrier();
                asm volatile("" ::: "memory");
            } else if (u + 1 < NTOT) {
                asm volatile("s_waitcnt vmcnt(0)" ::: "memory");
                __builtin_amdgcn_s_barrier();
                asm volatile("" ::: "memory");
            }
        }

        // ---- epilogue: finish column sums across g-lanes, normalize, store ----
        #pragma unroll
        for (int m = 0; m < 2; ++m) {
            lsum[m] += __shfl_xor(lsum[m], 16);
            lsum[m] += __shfl_xor(lsum[m], 32);
        }
        #pragma unroll
        for (int m = 0; m < 2; ++m) {
            float linv = 1.0f / lsum[m];
            float* ob = out + ((size_t)b * S_ + q0w + m * 16 + c) * (H_ * D_) + h * D_;
            #pragma unroll
            for (int mt = 0; mt < 8; ++mt) {
                float4 o;
                o.x = acc[m][mt][0] * linv; o.y = acc[m][mt][1] * linv;
                o.z = acc[m][mt][2] * linv; o.w = acc[m][mt][3] * linv;
                *(float4*)(ob + mt * 16 + 4 * g) = o;
            }
        }
    };

    run_tile(qtA, 0, NTA);
    run_tile(qtB, NTA, NTOT - NTA);
}

// ---------------------------------------------------------------------------
extern "C" void kernel_launch(void* const* d_in, const int* in_sizes, int n_in,
                              void* d_out, int out_size, void* d_ws, size_t ws_size,
                              hipStream_t stream) {
    const float* q = (const float*)d_in[0];
    const float* k = (const float*)d_in[1];
    const float* v = (const float*)d_in[2];
    float* out = (float*)d_out;

    unsigned short* kbuf = (unsigned short*)d_ws;                       // 8 MB
    unsigned short* vbuf = kbuf + (size_t)B_ * KVH_ * S_ * D_;          // 8 MB

    prepass<<<3072, 256, 0, stream>>>(k, v, kbuf, vbuf);
    attn_fwd<<<NBLK, 256, 0, stream>>>(q, kbuf, vbuf, out);
}

// Round 5
// 128.520 us; speedup vs baseline: 7.0554x; 1.1059x over previous
//
#include <hip/hip_runtime.h>
#include <hip/hip_bf16.h>
#include <stdint.h>

#define B_    2
#define S_    2048
#define H_    32
#define KVH_  8
#define D_    128
#define NBLK  512                // (B*H)=64 bh-pairs x 8 qtile-pairs
#define NTOT_ 34                 // (2*qtA+2) + (2*qtB+2), qtA+qtB = 15 (uniform)

typedef __bf16 bf16x8 __attribute__((ext_vector_type(8)));
typedef unsigned short u16x8 __attribute__((ext_vector_type(8)));
typedef unsigned int u32x4 __attribute__((ext_vector_type(4)));
typedef float f32x4 __attribute__((ext_vector_type(4)));

// softmax scale * log2(e), folded into Q at fragment load -> scores in log2 domain
__device__ constexpr float SCALE_LOG2E = 0.08838834764831845f * 1.4426950408889634f;
__device__ constexpr float DEFER_LOG2  = 11.0f;   // defer-max threshold: P <= 2^11

__device__ __forceinline__ unsigned short f2bf(float f) {
    unsigned int u = __builtin_bit_cast(unsigned int, f);
    u = (u + 0x7FFFu + ((u >> 16) & 1u)) >> 16;   // RNE
    return (unsigned short)u;
}

__device__ __forceinline__ unsigned int cvt_pk_bf16(float lo, float hi) {
    unsigned int r;
    asm("v_cvt_pk_bf16_f32 %0, %1, %2" : "=v"(r) : "v"(lo), "v"(hi));
    return r;
}

__device__ __forceinline__ void gload16(const unsigned short* gsrc, unsigned short* ldst) {
    __builtin_amdgcn_global_load_lds(
        (const __attribute__((address_space(1))) unsigned int*)gsrc,
        (__attribute__((address_space(3))) unsigned int*)ldst,
        16, 0, 0);
}

// ---------------------------------------------------------------------------
// Merged prepass (unchanged layouts).
// kbuf chunk ((((b*KVH+kvh)*128 + kb)*4 + ch)*64 + l)*8 :
//   K[b][s = kb*16 + (l&15)][kvh][d = ch*32 + (l>>4)*8 + j]
// vbuf chunk ((((b*KVH+kvh)*64 + vb)*8 + mt)*64 + l)*8 :
//   V[b][s = vb*32 + (l>>4)*8 + j][kvh][d = mt*16 + (l&15)]
// ---------------------------------------------------------------------------
__global__ __launch_bounds__(256) void prepass(const float* __restrict__ k,
                                               const float* __restrict__ v,
                                               unsigned short* __restrict__ kbuf,
                                               unsigned short* __restrict__ vbuf) {
    if (blockIdx.x < 2048) {
        int tid = blockIdx.x * 256 + threadIdx.x;
        int l   = tid & 63;
        int ch  = (tid >> 6) & 3;
        int kb  = (tid >> 8) & 127;
        int kvh = (tid >> 15) & 7;
        int b   = tid >> 18;
        int s   = kb * 16 + (l & 15);
        int d0  = ch * 32 + (l >> 4) * 8;
        const float* src = k + (((size_t)b * S_ + s) * KVH_ + kvh) * D_ + d0;
        float4 x = ((const float4*)src)[0];
        float4 y = ((const float4*)src)[1];
        u16x8 o;
        o[0] = f2bf(x.x); o[1] = f2bf(x.y); o[2] = f2bf(x.z); o[3] = f2bf(x.w);
        o[4] = f2bf(y.x); o[5] = f2bf(y.y); o[6] = f2bf(y.z); o[7] = f2bf(y.w);
        *(u16x8*)(kbuf + ((size_t)(((b * KVH_ + kvh) * 128 + kb) * 4 + ch) * 64 + l) * 8) = o;
    } else {
        __shared__ float tile[32][130];
        int bid = blockIdx.x - 2048;           // 0..1023
        int vb  = bid & 63;
        int kvh = (bid >> 6) & 7;
        int b   = bid >> 9;
        int t   = threadIdx.x;

        int s   = t >> 3;
        int c16 = (t & 7) * 16;
        const float* src = v + (((size_t)b * S_ + vb * 32 + s) * KVH_ + kvh) * D_ + c16;
        #pragma unroll
        for (int j = 0; j < 4; ++j) {
            float4 x = ((const float4*)src)[j];
            tile[s][c16 + 4 * j + 0] = x.x; tile[s][c16 + 4 * j + 1] = x.y;
            tile[s][c16 + 4 * j + 2] = x.z; tile[s][c16 + 4 * j + 3] = x.w;
        }
        __syncthreads();

        #pragma unroll
        for (int i = 0; i < 2; ++i) {
            int ci = t + i * 256;
            int mt = ci >> 6, l = ci & 63, c = l & 15, g = l >> 4;
            u16x8 o;
            #pragma unroll
            for (int j = 0; j < 8; ++j) o[j] = f2bf(tile[g * 8 + j][mt * 16 + c]);
            *(u16x8*)(vbuf + ((size_t)(((b * KVH_ + kvh) * 64 + vb) * 8 + mt) * 64 + l) * 8) = o;
        }
    }
}

// ---------------------------------------------------------------------------
// Main kernel: 4 waves, block runs q-tiles (qt, 15-qt): uniform 34 KV-iters
// of 64 keys. K,V double-buffered (64KB LDS). Deferred-PV software pipeline:
// per iter u issue QK(u) -> PV(u-1) -> softmax(u); PV fills the MFMA pipe
// while softmax waits on QK results. P register state double-banked (pfA/pfB)
// with the loop unrolled x2 so all indexing is static.
// V is staged one iter EARLY (V(u) at top of iter u, consumed in iter u+1) so
// the deferred PV never collides with the double-buffer rotation.
// ---------------------------------------------------------------------------
__global__ __launch_bounds__(256, 2)
void attn_fwd(const float* __restrict__ q,
              const unsigned short* __restrict__ kbuf,
              const unsigned short* __restrict__ vbuf,
              float* __restrict__ out)
{
    // XCD-chunked swizzle (512 % 8 == 0 -> bijective)
    int pid = blockIdx.x;
    int lid = (pid & 7) * (NBLK / 8) + (pid >> 3);
    int p   = lid & 7;                    // q-tile pair index
    int bh  = lid >> 3;
    int b   = bh >> 5, h = bh & 31, kvh = h >> 2;
    const int qtA = 15 - p;               // long tile first
    const int NTA = 2 * qtA + 2;
    const int qtB = p;

    const int tid = threadIdx.x, wave = tid >> 6, lane = tid & 63;
    const int c = lane & 15, g = lane >> 4;

    __shared__ __align__(16) unsigned short ldsK[2][8192];   // 16KB per buf
    __shared__ __align__(16) unsigned short ldsV[2][8192];

    const unsigned short* kfb = kbuf + (size_t)(b * KVH_ + kvh) * (S_ * D_);
    const unsigned short* vfb = vbuf + (size_t)(b * KVH_ + kvh) * (S_ * D_);

    // bpermute source-lane byte addresses for the P redistribution
    const int addr0 = (c + 16 * ((2 * g) & 3)) * 4;        // out words s=0,1
    const int addr1 = (c + 16 * ((2 * g + 1) & 3)) * 4;    // out words s=2,3
    const bool ghi = (g >= 2);

    auto kvt = [&](int u) { return (u < NTA) ? u : (u - NTA); };
    auto stageK = [&](int u) {              // -> ldsK[u&1]
        const unsigned short* ks = kfb + (size_t)kvt(u) * 8192;
        unsigned short* ld = &ldsK[u & 1][0];
        #pragma unroll
        for (int i = 0; i < 4; ++i) {
            int seg = wave * 4 + i;
            gload16(ks + seg * 512 + lane * 8, ld + seg * 512);
        }
    };
    auto stageV = [&](int u) {              // -> ldsV[u&1]
        const unsigned short* vs = vfb + (size_t)kvt(u) * 8192;
        unsigned short* ld = &ldsV[u & 1][0];
        #pragma unroll
        for (int i = 0; i < 4; ++i) {
            int seg = wave * 4 + i;
            gload16(vs + seg * 512 + lane * 8, ld + seg * 512);
        }
    };

    // prologue: K(0) in flight
    stageK(0);
    asm volatile("s_waitcnt vmcnt(0)" ::: "memory");
    __builtin_amdgcn_s_barrier();
    asm volatile("" ::: "memory");

    auto run_tile = [&](int qt, int u0, int NT) {
        const int q0w = qt * 128 + wave * 32;

        // Q fragments (B-operand), scale*log2e folded
        bf16x8 qf[2][4];
        #pragma unroll
        for (int m = 0; m < 2; ++m) {
            const float* qp = q + ((size_t)b * S_ + q0w + m * 16 + c) * (H_ * D_) + h * D_ + g * 8;
            #pragma unroll
            for (int ch = 0; ch < 4; ++ch) {
                float4 a  = ((const float4*)(qp + ch * 32))[0];
                float4 bb = ((const float4*)(qp + ch * 32))[1];
                u16x8 tt;
                tt[0] = f2bf(a.x * SCALE_LOG2E);  tt[1] = f2bf(a.y * SCALE_LOG2E);
                tt[2] = f2bf(a.z * SCALE_LOG2E);  tt[3] = f2bf(a.w * SCALE_LOG2E);
                tt[4] = f2bf(bb.x * SCALE_LOG2E); tt[5] = f2bf(bb.y * SCALE_LOG2E);
                tt[6] = f2bf(bb.z * SCALE_LOG2E); tt[7] = f2bf(bb.w * SCALE_LOG2E);
                qf[m][ch] = __builtin_bit_cast(bf16x8, tt);
            }
        }

        f32x4 acc[2][8];
        #pragma unroll
        for (int m = 0; m < 2; ++m)
            #pragma unroll
            for (int mt = 0; mt < 8; ++mt) acc[m][mt] = (f32x4){0.f, 0.f, 0.f, 0.f};
        float mrun[2], lsum[2];
        #pragma unroll
        for (int m = 0; m < 2; ++m) { mrun[m] = -INFINITY; lsum[m] = 0.f; }

        u32x4 pfA[2][2], pfB[2][2];         // double-banked packed-P state

        // one pipeline body. Buffer parities are compile-time via ODD.
        auto body = [&](int u, int it, int NT_, auto& pfW, auto& pfR, int ODD) {
            if (u + 1 < NTOT_) stageK(u + 1);        // -> ldsK[ODD^1]
            stageV(u);                               // -> ldsV[ODD]
            const bool act = (it < NT_ - 1) || (wave >= 2);
            const int k0 = it * 64;
            f32x4 sv[2][4];

            if (act) {
                __builtin_amdgcn_s_setprio(1);
                #pragma unroll
                for (int t2 = 0; t2 < 4; ++t2) {
                    bf16x8 kf[4];
                    #pragma unroll
                    for (int ch = 0; ch < 4; ++ch)
                        kf[ch] = *(const bf16x8*)&ldsK[ODD][(t2 * 4 + ch) * 512 + lane * 8];
                    sv[0][t2] = (f32x4){0.f, 0.f, 0.f, 0.f};
                    sv[1][t2] = (f32x4){0.f, 0.f, 0.f, 0.f};
                    #pragma unroll
                    for (int ch = 0; ch < 4; ++ch) {
                        sv[0][t2] = __builtin_amdgcn_mfma_f32_16x16x32_bf16(kf[ch], qf[0][ch], sv[0][t2], 0, 0, 0);
                        sv[1][t2] = __builtin_amdgcn_mfma_f32_16x16x32_bf16(kf[ch], qf[1][ch], sv[1][t2], 0, 0, 0);
                    }
                }
                __builtin_amdgcn_s_setprio(0);
            }

            if (it > 0) {   // deferred PV(u-1): ldsV[ODD^1], pfR
                __builtin_amdgcn_s_setprio(1);
                #pragma unroll
                for (int kc = 0; kc < 2; ++kc) {
                    bf16x8 pb0 = __builtin_bit_cast(bf16x8, pfR[0][kc]);
                    bf16x8 pb1 = __builtin_bit_cast(bf16x8, pfR[1][kc]);
                    #pragma unroll
                    for (int mt = 0; mt < 8; ++mt) {
                        bf16x8 vf = *(const bf16x8*)&ldsV[ODD ^ 1][(kc * 8 + mt) * 512 + lane * 8];
                        acc[0][mt] = __builtin_amdgcn_mfma_f32_16x16x32_bf16(vf, pb0, acc[0][mt], 0, 0, 0);
                        acc[1][mt] = __builtin_amdgcn_mfma_f32_16x16x32_bf16(vf, pb1, acc[1][mt], 0, 0, 0);
                    }
                }
                __builtin_amdgcn_s_setprio(0);
            }

            if (act) {
                // causal mask: key = k0+16t2+4g+r vs q-col = q0w+16m+c
                #pragma unroll
                for (int m = 0; m < 2; ++m) {
                    if (k0 + 63 > q0w + m * 16) {
                        #pragma unroll
                        for (int t2 = 0; t2 < 4; ++t2)
                            #pragma unroll
                            for (int r = 0; r < 4; ++r)
                                if (k0 + 16 * t2 + 4 * g + r > q0w + m * 16 + c) sv[m][t2][r] = -INFINITY;
                    }
                }

                // defer-max online softmax (stats lane-local per q-column)
                float lm[2];
                #pragma unroll
                for (int m = 0; m < 2; ++m) {
                    float a0 = fmaxf(fmaxf(sv[m][0][0], sv[m][0][1]), fmaxf(sv[m][0][2], sv[m][0][3]));
                    float a1 = fmaxf(fmaxf(sv[m][1][0], sv[m][1][1]), fmaxf(sv[m][1][2], sv[m][1][3]));
                    float a2 = fmaxf(fmaxf(sv[m][2][0], sv[m][2][1]), fmaxf(sv[m][2][2], sv[m][2][3]));
                    float a3 = fmaxf(fmaxf(sv[m][3][0], sv[m][3][1]), fmaxf(sv[m][3][2], sv[m][3][3]));
                    lm[m] = fmaxf(fmaxf(a0, a1), fmaxf(a2, a3));
                }
                bool ok = (lm[0] <= mrun[0] + DEFER_LOG2) && (lm[1] <= mrun[1] + DEFER_LOG2);
                if (!__all(ok)) {
                    #pragma unroll
                    for (int m = 0; m < 2; ++m) {
                        float mx = lm[m];
                        mx = fmaxf(mx, __shfl_xor(mx, 16));
                        mx = fmaxf(mx, __shfl_xor(mx, 32));
                        float mn = fmaxf(mrun[m], mx);
                        float al = exp2f(mrun[m] - mn);
                        mrun[m] = mn;
                        lsum[m] *= al;
                        #pragma unroll
                        for (int mt = 0; mt < 8; ++mt) {
                            acc[m][mt][0] *= al; acc[m][mt][1] *= al;
                            acc[m][mt][2] *= al; acc[m][mt][3] *= al;
                        }
                    }
                }

                // P = exp2(S - m); per-lane partial sums; pack into pfW
                #pragma unroll
                for (int m = 0; m < 2; ++m) {
                    float pvv[4][4];
                    #pragma unroll
                    for (int t2 = 0; t2 < 4; ++t2)
                        #pragma unroll
                        for (int r = 0; r < 4; ++r)
                            pvv[t2][r] = exp2f(sv[m][t2][r] - mrun[m]);
                    float s01 = (pvv[0][0] + pvv[0][1]) + (pvv[0][2] + pvv[0][3])
                              + (pvv[1][0] + pvv[1][1]) + (pvv[1][2] + pvv[1][3]);
                    float s23 = (pvv[2][0] + pvv[2][1]) + (pvv[2][2] + pvv[2][3])
                              + (pvv[3][0] + pvv[3][1]) + (pvv[3][2] + pvv[3][3]);
                    lsum[m] += s01 + s23;
                    #pragma unroll
                    for (int kc = 0; kc < 2; ++kc) {
                        unsigned int we0 = cvt_pk_bf16(pvv[2 * kc][0], pvv[2 * kc][1]);
                        unsigned int we1 = cvt_pk_bf16(pvv[2 * kc][2], pvv[2 * kc][3]);
                        unsigned int wo0 = cvt_pk_bf16(pvv[2 * kc + 1][0], pvv[2 * kc + 1][1]);
                        unsigned int wo1 = cvt_pk_bf16(pvv[2 * kc + 1][2], pvv[2 * kc + 1][3]);
                        u32x4 W;
                        {
                            int x0 = __builtin_amdgcn_ds_bpermute(addr0, (int)we0);
                            int x1 = __builtin_amdgcn_ds_bpermute(addr0, (int)wo0);
                            W[0] = (unsigned int)(ghi ? x1 : x0);
                            int x2 = __builtin_amdgcn_ds_bpermute(addr0, (int)we1);
                            int x3 = __builtin_amdgcn_ds_bpermute(addr0, (int)wo1);
                            W[1] = (unsigned int)(ghi ? x3 : x2);
                            int x4 = __builtin_amdgcn_ds_bpermute(addr1, (int)we0);
                            int x5 = __builtin_amdgcn_ds_bpermute(addr1, (int)wo0);
                            W[2] = (unsigned int)(ghi ? x5 : x4);
                            int x6 = __builtin_amdgcn_ds_bpermute(addr1, (int)we1);
                            int x7 = __builtin_amdgcn_ds_bpermute(addr1, (int)wo1);
                            W[3] = (unsigned int)(ghi ? x7 : x6);
                        }
                        pfW[m][kc] = W;
                    }
                }
            }

            asm volatile("s_waitcnt vmcnt(0)" ::: "memory");
            __builtin_amdgcn_s_barrier();
            asm volatile("" ::: "memory");
        };

        for (int it = 0; it < NT; it += 2) {
            body(u0 + it,     it,     NT, pfA, pfB, 0);   // even: K in ldsK[0]
            body(u0 + it + 1, it + 1, NT, pfB, pfA, 1);   // odd:  K in ldsK[1]
        }

        // tile epilogue: final deferred PV (only waves whose last iter was
        // active, i.e. wave>=2), then normalize + store.
        if (wave >= 2) {
            #pragma unroll
            for (int kc = 0; kc < 2; ++kc) {
                bf16x8 pb0 = __builtin_bit_cast(bf16x8, pfB[0][kc]);
                bf16x8 pb1 = __builtin_bit_cast(bf16x8, pfB[1][kc]);
                #pragma unroll
                for (int mt = 0; mt < 8; ++mt) {
                    bf16x8 vf = *(const bf16x8*)&ldsV[1][(kc * 8 + mt) * 512 + lane * 8];
                    acc[0][mt] = __builtin_amdgcn_mfma_f32_16x16x32_bf16(vf, pb0, acc[0][mt], 0, 0, 0);
                    acc[1][mt] = __builtin_amdgcn_mfma_f32_16x16x32_bf16(vf, pb1, acc[1][mt], 0, 0, 0);
                }
            }
        }

        #pragma unroll
        for (int m = 0; m < 2; ++m) {
            lsum[m] += __shfl_xor(lsum[m], 16);
            lsum[m] += __shfl_xor(lsum[m], 32);
        }
        #pragma unroll
        for (int m = 0; m < 2; ++m) {
            float linv = 1.0f / lsum[m];
            float* ob = out + ((size_t)b * S_ + q0w + m * 16 + c) * (H_ * D_) + h * D_;
            #pragma unroll
            for (int mt = 0; mt < 8; ++mt) {
                float4 o;
                o.x = acc[m][mt][0] * linv; o.y = acc[m][mt][1] * linv;
                o.z = acc[m][mt][2] * linv; o.w = acc[m][mt][3] * linv;
                *(float4*)(ob + mt * 16 + 4 * g) = o;
            }
        }
    };

    run_tile(qtA, 0, NTA);
    run_tile(qtB, NTA, NTOT_ - NTA);
}

// ---------------------------------------------------------------------------
extern "C" void kernel_launch(void* const* d_in, const int* in_sizes, int n_in,
                              void* d_out, int out_size, void* d_ws, size_t ws_size,
                              hipStream_t stream) {
    const float* q = (const float*)d_in[0];
    const float* k = (const float*)d_in[1];
    const float* v = (const float*)d_in[2];
    float* out = (float*)d_out;

    unsigned short* kbuf = (unsigned short*)d_ws;                       // 8 MB
    unsigned short* vbuf = kbuf + (size_t)B_ * KVH_ * S_ * D_;          // 8 MB

    prepass<<<3072, 256, 0, stream>>>(k, v, kbuf, vbuf);
    attn_fwd<<<NBLK, 256, 0, stream>>>(q, kbuf, vbuf, out);
}